// Round 6
// baseline (397.008 us; speedup 1.0000x reference)
//
#include <hip/hip_runtime.h>
#include <hip/hip_bf16.h>
#include <math.h>

#define BB    1024
#define FIN   128
#define NOUT  10000
#define NBLK  79          // 128-col strips
#define NK    16
#define NPART (NBLK * 2)
#define LDX   136         // LDS stride (shorts) for the X tile

typedef __attribute__((ext_vector_type(8))) short short8;
typedef __attribute__((ext_vector_type(4))) float floatx4;

__device__ __forceinline__ unsigned packbf(float a, float b) {
    __hip_bfloat162 h = __float22bfloat162_rn(make_float2(a, b));
    union { __hip_bfloat162 h2; unsigned u; } v;
    v.h2 = h;
    return v.u;
}

// async global->LDS, 16B per lane; LDS dest = wave-uniform base + lane*16.
__device__ __forceinline__ void async16(const void* g, void* l) {
    __builtin_amdgcn_global_load_lds(
        (const __attribute__((address_space(1))) unsigned int*)g,
        (__attribute__((address_space(3))) unsigned int*)l, 16, 0, 0);
}

// ---------------------------------------------------------------------------
// Kernel A: per-row input inverse-norm + margin params
__global__ void rowprep(const float* __restrict__ X, const float* __restrict__ factor,
                        float* __restrict__ xinv, float* __restrict__ fa_out,
                        float* __restrict__ thr_out) {
    int b = blockIdx.x;
    int lane = threadIdx.x;
    float v0 = X[b * FIN + lane];
    float v1 = X[b * FIN + 64 + lane];
    float s = v0 * v0 + v1 * v1;
    #pragma unroll
    for (int off = 32; off > 0; off >>= 1) s += __shfl_down(s, off);
    if (lane == 0) {
        float n = sqrtf(s);
        xinv[b] = 1.0f / fmaxf(n, 1e-12f);
        float fa = powf(1.5f, factor[b] * (1.0f / 12.0f)) * 0.5f;
        fa_out[b] = fa;
        thr_out[b] = (float)M_PI - fa;
    }
}

// ---------------------------------------------------------------------------
// Kernel W: one-time W conversion, LDS-staged & fully coalesced.
// Output layout: [k][ch][strip][idx64][256B column], where for column o:
//   strip=o>>7, g=o&127, ch=(g>>5)&1, idx64=((g>>6)<<5)|(g&31).
// Within a column, true chunk tc (features tc*8..tc*8+7) sits at byte
// offset ((tc ^ (o&15)) * 16)  -> conflict-free b128 reads in gemm.
__global__ __launch_bounds__(256) void wconv(const float* __restrict__ W,
                                             unsigned char* __restrict__ Wbf) {
    __shared__ float xs2[128 * 128];   // [f][o] fp32 (64 KB)
    __shared__ float sq2[256];
    __shared__ float wis[128];

    const int tid = threadIdx.x;
    const int k = blockIdx.x / NBLK;
    const int strip = blockIdx.x - k * NBLK;
    const int o0 = strip * 128;

    // stage 128f x 128o = 4096 float4; 256 threads -> 16 iters (BUGFIX: was 64)
    #pragma unroll
    for (int it = 0; it < 16; it++) {
        int idx = it * 256 + tid;      // float4 index 0..4095
        int f = idx >> 5;              // 32 float4 per 128-col row
        int c4 = idx & 31;
        int o = o0 + c4 * 4;
        float4 v = make_float4(0.f, 0.f, 0.f, 0.f);
        if (o < NOUT)
            v = *(const float4*)(W + ((size_t)k * FIN + f) * NOUT + o);
        *(float4*)(xs2 + f * 128 + c4 * 4) = v;
    }
    __syncthreads();

    const int col = tid & 127;
    const int half = tid >> 7;
    float s = 0.0f;
    #pragma unroll 8
    for (int f2 = 0; f2 < 64; f2++) {
        float x = xs2[(half * 64 + f2) * 128 + col];
        s = fmaf(x, x, s);
    }
    sq2[half * 128 + col] = s;
    __syncthreads();
    if (tid < 128)
        wis[tid] = 1.0f / fmaxf(sqrtf(sq2[tid] + sq2[tid + 128]), 1e-12f);
    __syncthreads();

    const float wi = wis[col];
    const int ch = (col >> 5) & 1;
    const int idx64 = ((col >> 6) << 5) | (col & 31);
    unsigned char* colbase =
        Wbf + ((((size_t)k * 2 + ch) * NBLK + strip) * 64 + idx64) * 256;
    #pragma unroll
    for (int tcl = 0; tcl < 8; tcl++) {
        int tc = half * 8 + tcl;
        float v0 = xs2[(tc * 8 + 0) * 128 + col] * wi;
        float v1 = xs2[(tc * 8 + 1) * 128 + col] * wi;
        float v2 = xs2[(tc * 8 + 2) * 128 + col] * wi;
        float v3 = xs2[(tc * 8 + 3) * 128 + col] * wi;
        float v4 = xs2[(tc * 8 + 4) * 128 + col] * wi;
        float v5 = xs2[(tc * 8 + 5) * 128 + col] * wi;
        float v6 = xs2[(tc * 8 + 6) * 128 + col] * wi;
        float v7 = xs2[(tc * 8 + 7) * 128 + col] * wi;
        uint4 u;
        u.x = packbf(v0, v1);
        u.y = packbf(v2, v3);
        u.z = packbf(v4, v5);
        u.w = packbf(v6, v7);
        *(uint4*)(colbase + ((tc ^ (col & 15)) * 16)) = u;
    }
}

// ---------------------------------------------------------------------------
// Kernel B: MFMA GEMM + max-over-k + partial online-softmax.
// 32 ck-steps (16 sub-centers x 2 col-halves); 16 KB B buffers, double-
// buffered via async16; LDS 34.8 KB union -> 3 blocks/CU (VGPR-capped at
// 3 waves/SIMD) -> 632 blocks all co-resident (zero tail), 12 waves/CU.
__global__ __launch_bounds__(256, 3) void gemm_mx(
    const float* __restrict__ X, const unsigned char* __restrict__ Wbf,
    const int* __restrict__ label, const float* __restrict__ xinv,
    float2* __restrict__ partial, float* __restrict__ cosl) {

    __shared__ union {
        short xs[128 * LDX];   // 34816 B, X staging
        short bb[2][8192];     // 2 x 16 KB B buffers
    } u;

    const int tid  = threadIdx.x;
    const int lane = tid & 63;
    const int w    = tid >> 6;
    const int l15  = lane & 15;
    const int q    = lane >> 4;
    const int wm   = w & 1;
    const int wn   = w >> 1;

    // XCD-aware decode: ids {group*64 + y*8 + xcd} -> jb = group*8+xcd
    const int id    = blockIdx.x;
    const int group = id >> 6;
    const int sub   = id & 63;
    const int jb    = group * 8 + (sub & 7);
    const int y     = sub >> 3;
    if (jb >= NBLK) return;
    const int r0 = y * 128;

    // ---- stage X tile as bf16 with xinv folded ----
    #pragma unroll
    for (int it = 0; it < 16; it++) {
        int idx = it * 256 + tid;
        int row = idx >> 5;
        int c4  = idx & 31;
        const float4 v = *(const float4*)(X + (size_t)(r0 + row) * FIN + c4 * 4);
        float xi = xinv[r0 + row];
        uint2 p;
        p.x = packbf(v.x * xi, v.y * xi);
        p.y = packbf(v.z * xi, v.w * xi);
        *(uint2*)(u.xs + row * LDX + c4 * 4) = p;
    }
    __syncthreads();

    short8 af[4][4];
    #pragma unroll
    for (int mt = 0; mt < 4; mt++)
        #pragma unroll
        for (int kk = 0; kk < 4; kk++)
            af[mt][kk] = *(const short8*)(u.xs + (wm * 64 + mt * 16 + l15) * LDX + kk * 32 + q * 8);
    __syncthreads();   // X area now reusable as B buffers

    auto issue = [&](int ck) {
        const unsigned char* g = Wbf + ((size_t)ck * NBLK + jb) * 16384
                                 + (size_t)(w * 4) * 1024 + (size_t)lane * 16;
        short* d = u.bb[ck & 1] + w * 2048;
        #pragma unroll
        for (int i = 0; i < 4; i++) async16(g + i * 1024, d + i * 512);
    };

    issue(0);

    floatx4 maxv[4][4];
    #pragma unroll
    for (int mt = 0; mt < 4; mt++)
        #pragma unroll
        for (int nt = 0; nt < 4; nt++)
            #pragma unroll
            for (int r = 0; r < 4; r++)
                maxv[mt][nt][r] = -INFINITY;

    for (int ck = 0; ck < 2 * NK; ck++) {
        __syncthreads();   // prefetch(ck) landed; prior buffer reads done
        if (ck < 2 * NK - 1) issue(ck + 1);
        const short* wt = u.bb[ck & 1];
        const int ch = ck & 1;

        #pragma unroll
        for (int n2 = 0; n2 < 2; n2++) {
            const int bidx = wn * 32 + n2 * 16 + l15;   // column index in buffer
            floatx4 acc[4];
            #pragma unroll
            for (int mt = 0; mt < 4; mt++) acc[mt] = (floatx4){0.f, 0.f, 0.f, 0.f};
            #pragma unroll
            for (int kk = 0; kk < 4; kk++) {
                short8 bf = *(const short8*)(wt + bidx * 128 + (((kk * 4 + q) ^ l15) * 8));
                #pragma unroll
                for (int mt = 0; mt < 4; mt++)
                    acc[mt] = __builtin_amdgcn_mfma_f32_16x16x32_bf16(af[mt][kk], bf, acc[mt], 0, 0, 0);
            }
            const int nt = ch * 2 + n2;
            #pragma unroll
            for (int mt = 0; mt < 4; mt++)
                #pragma unroll
                for (int r = 0; r < 4; r++)
                    maxv[mt][nt][r] = fmaxf(maxv[mt][nt][r], acc[mt][r]);
        }
    }

    // ---- epilogue: per-row partial online-softmax (label col excluded) ----
    const int o0 = jb * 128;
    #pragma unroll
    for (int mt = 0; mt < 4; mt++) {
        #pragma unroll
        for (int rr = 0; rr < 4; rr++) {
            int row = r0 + wm * 64 + mt * 16 + q * 4 + rr;
            int lb = label[row];
            float m = -1e30f, s = 0.f;
            #pragma unroll
            for (int nt = 0; nt < 4; nt++) {
                int o = o0 + wn * 64 + nt * 16 + l15;
                if (o < NOUT) {
                    float c = maxv[mt][nt][rr];
                    if (o == lb) {
                        cosl[row] = c;
                    } else {
                        float l = 64.0f * fminf(fmaxf(c, -1.0f + 1e-6f), 1.0f - 1e-6f);
                        if (l > m) { s = s * __expf(m - l) + 1.0f; m = l; }
                        else       { s += __expf(l - m); }
                    }
                }
            }
            #pragma unroll
            for (int off = 1; off <= 8; off <<= 1) {
                float m2 = __shfl_xor(m, off);
                float s2 = __shfl_xor(s, off);
                float M = fmaxf(m, m2);
                s = s * __expf(m - M) + s2 * __expf(m2 - M);
                m = M;
            }
            if (l15 == 0) partial[(size_t)row * NPART + jb * 2 + wn] = make_float2(m, s);
        }
    }
}

// ---------------------------------------------------------------------------
// Fallback GEMM (round-3 path) used when ws_size can't hold Wbf.
__global__ __launch_bounds__(256, 2) void gemm_stats(
    const float* __restrict__ X, const float* __restrict__ W,
    const int* __restrict__ label, const float* __restrict__ xinv,
    float2* __restrict__ partial, float* __restrict__ cosl) {

    __shared__ short xs[128 * LDX];
    __shared__ short wt[128 * LDX];
    __shared__ float sqs[128][2];

    const int tid  = threadIdx.x;
    const int lane = tid & 63;
    const int w    = tid >> 6;
    const int l15  = lane & 15;
    const int q    = lane >> 4;
    const int wm   = w & 1;
    const int wn   = w >> 1;

    const int id    = blockIdx.x;
    const int group = id >> 6;
    const int sub   = id & 63;
    const int jb    = group * 8 + (sub & 7);
    const int y     = sub >> 3;
    if (jb >= NBLK) return;
    const int r0 = y * 128;
    const int o0 = jb * 128;

    #pragma unroll
    for (int it = 0; it < 16; it++) {
        int idx = it * 256 + tid;
        int row = idx >> 5;
        int c4  = idx & 31;
        const float4 v = *(const float4*)(X + (size_t)(r0 + row) * FIN + c4 * 4);
        uint2 p;
        p.x = packbf(v.x, v.y);
        p.y = packbf(v.z, v.w);
        *(uint2*)(xs + row * LDX + c4 * 4) = p;
    }

    const int st_o = (w & 1) * 64 + lane;
    const int st_f = (w >> 1) * 64;
    const int st_h = w >> 1;
    const int go   = o0 + st_o;
    const bool ov  = go < NOUT;

    float rw[64];
    {
        const float* Wp = W + (size_t)st_f * NOUT + go;
        #pragma unroll
        for (int g = 0; g < 16; g++)
            #pragma unroll
            for (int c = 0; c < 4; c++)
                rw[g * 4 + c] = ov ? Wp[(size_t)(g * 4 + c) * NOUT] : 0.0f;
    }
    __syncthreads();

    short8 af[4][4];
    #pragma unroll
    for (int mt = 0; mt < 4; mt++)
        #pragma unroll
        for (int kk = 0; kk < 4; kk++)
            af[mt][kk] = *(const short8*)(xs + (wm * 64 + mt * 16 + l15) * LDX + kk * 32 + q * 8);

    floatx4 maxv[4][4];
    #pragma unroll
    for (int mt = 0; mt < 4; mt++)
        #pragma unroll
        for (int nt = 0; nt < 4; nt++)
            #pragma unroll
            for (int r = 0; r < 4; r++)
                maxv[mt][nt][r] = -INFINITY;

    for (int k = 0; k < NK; k++) {
        float sq = 0.0f;
        uint2 pk[16];
        #pragma unroll
        for (int g = 0; g < 16; g++) {
            float a0 = rw[g * 4 + 0], a1 = rw[g * 4 + 1];
            float a2 = rw[g * 4 + 2], a3 = rw[g * 4 + 3];
            sq = fmaf(a0, a0, sq); sq = fmaf(a1, a1, sq);
            sq = fmaf(a2, a2, sq); sq = fmaf(a3, a3, sq);
            pk[g].x = packbf(a0, a1);
            pk[g].y = packbf(a2, a3);
        }
        __syncthreads();
        #pragma unroll
        for (int g = 0; g < 16; g++)
            *(uint2*)(wt + st_o * LDX + st_f + g * 4) = pk[g];
        sqs[st_o][st_h] = sq;
        __syncthreads();

        if (k < NK - 1) {
            const float* Wn = W + ((size_t)(k + 1) * FIN + st_f) * NOUT + go;
            #pragma unroll
            for (int g = 0; g < 16; g++)
                #pragma unroll
                for (int c = 0; c < 4; c++)
                    rw[g * 4 + c] = ov ? Wn[(size_t)(g * 4 + c) * NOUT] : 0.0f;
        }

        float wv[4];
        #pragma unroll
        for (int nt = 0; nt < 4; nt++) {
            int col = wn * 64 + nt * 16 + l15;
            wv[nt] = 1.0f / fmaxf(sqrtf(sqs[col][0] + sqs[col][1]), 1e-12f);
        }

        #pragma unroll
        for (int h = 0; h < 2; h++) {
            floatx4 acc[4][2];
            #pragma unroll
            for (int mt = 0; mt < 4; mt++) {
                acc[mt][0] = (floatx4){0.f, 0.f, 0.f, 0.f};
                acc[mt][1] = (floatx4){0.f, 0.f, 0.f, 0.f};
            }
            #pragma unroll
            for (int kk = 0; kk < 4; kk++) {
                short8 bf0 = *(const short8*)(wt + (wn * 64 + (h * 2 + 0) * 16 + l15) * LDX + kk * 32 + q * 8);
                short8 bf1 = *(const short8*)(wt + (wn * 64 + (h * 2 + 1) * 16 + l15) * LDX + kk * 32 + q * 8);
                #pragma unroll
                for (int mt = 0; mt < 4; mt++) {
                    acc[mt][0] = __builtin_amdgcn_mfma_f32_16x16x32_bf16(af[mt][kk], bf0, acc[mt][0], 0, 0, 0);
                    acc[mt][1] = __builtin_amdgcn_mfma_f32_16x16x32_bf16(af[mt][kk], bf1, acc[mt][1], 0, 0, 0);
                }
            }
            #pragma unroll
            for (int mt = 0; mt < 4; mt++)
                #pragma unroll
                for (int n2 = 0; n2 < 2; n2++)
                    #pragma unroll
                    for (int r = 0; r < 4; r++)
                        maxv[mt][h * 2 + n2][r] =
                            fmaxf(maxv[mt][h * 2 + n2][r], acc[mt][n2][r] * wv[h * 2 + n2]);
        }
    }

    #pragma unroll
    for (int mt = 0; mt < 4; mt++) {
        #pragma unroll
        for (int rr = 0; rr < 4; rr++) {
            int row = r0 + wm * 64 + mt * 16 + q * 4 + rr;
            float xi = xinv[row];
            int lb = label[row];
            float m = -1e30f, s = 0.f;
            #pragma unroll
            for (int nt = 0; nt < 4; nt++) {
                int o = o0 + wn * 64 + nt * 16 + l15;
                if (o < NOUT) {
                    float c = maxv[mt][nt][rr] * xi;
                    if (o == lb) {
                        cosl[row] = c;
                    } else {
                        float l = 64.0f * fminf(fmaxf(c, -1.0f + 1e-6f), 1.0f - 1e-6f);
                        if (l > m) { s = s * __expf(m - l) + 1.0f; m = l; }
                        else       { s += __expf(l - m); }
                    }
                }
            }
            #pragma unroll
            for (int off = 1; off <= 8; off <<= 1) {
                float m2 = __shfl_xor(m, off);
                float s2 = __shfl_xor(s, off);
                float M = fmaxf(m, m2);
                s = s * __expf(m - M) + s2 * __expf(m2 - M);
                m = M;
            }
            if (l15 == 0) partial[(size_t)row * NPART + jb * 2 + wn] = make_float2(m, s);
        }
    }
}

// ---------------------------------------------------------------------------
// Kernel C1: per-row combine + margin -> (loss, corr) per row. No atomics.
__global__ void finalize_rows(const float2* __restrict__ partial, const float* __restrict__ cosl,
                              const float* __restrict__ fa, const float* __restrict__ thr,
                              float2* __restrict__ rowres) {
    int w = threadIdx.x >> 6;
    int lane = threadIdx.x & 63;
    int b = blockIdx.x * 4 + w;
    float m = -1e30f, s = 0.0f;
    for (int j = lane; j < NPART; j += 64) {
        float2 p = partial[(size_t)b * NPART + j];
        float M = fmaxf(m, p.x);
        s = s * __expf(m - M) + p.y * __expf(p.x - M);
        m = M;
    }
    #pragma unroll
    for (int off = 1; off < 64; off <<= 1) {
        float m2 = __shfl_xor(m, off);
        float s2 = __shfl_xor(s, off);
        float M = fmaxf(m, m2);
        s = s * __expf(m - M) + s2 * __expf(m2 - M);
        m = M;
    }
    if (lane == 0) {
        float c = fminf(fmaxf(cosl[b], -1.0f + 1e-6f), 1.0f - 1e-6f);
        float theta = acosf(c);
        float ll = (theta > thr[b]) ? 64.0f * c : 64.0f * cosf(theta + fa[b]);
        float M = fmaxf(m, ll);
        float S = s * __expf(m - M) + __expf(ll - M);
        rowres[b] = make_float2(M + logf(S) - ll, (ll > m) ? 100.0f : 0.0f);
    }
}

// Kernel C2: deterministic tree reduce of 1024 rows -> 2 scalars.
__global__ void finalize_sum(const float2* __restrict__ rowres, float* __restrict__ out) {
    __shared__ float sl[1024];
    __shared__ float sc[1024];
    int b = threadIdx.x;
    float2 v = rowres[b];
    sl[b] = v.x;
    sc[b] = v.y;
    __syncthreads();
    for (int st = 512; st > 0; st >>= 1) {
        if (b < st) { sl[b] += sl[b + st]; sc[b] += sc[b + st]; }
        __syncthreads();
    }
    if (b == 0) {
        out[0] = sl[0] * (1.0f / 1024.0f);
        out[1] = sc[0] * (1.0f / 1024.0f);
    }
}

// ---------------------------------------------------------------------------
extern "C" void kernel_launch(void* const* d_in, const int* in_sizes, int n_in,
                              void* d_out, int out_size, void* d_ws, size_t ws_size,
                              hipStream_t stream) {
    const float* X      = (const float*)d_in[0];
    const float* factor = (const float*)d_in[1];
    const int*   label  = (const int*)d_in[2];
    const float* W      = (const float*)d_in[3];
    float* out = (float*)d_out;
    float* ws  = (float*)d_ws;

    float*  xinv = ws;                        // 1024
    float*  fa   = ws + 1024;                 // 1024
    float*  thr  = ws + 2048;                 // 1024
    float*  cosl = ws + 3072;                 // 1024
    float2* rowres = (float2*)(ws + 4096);    // 1024 float2
    float2* partial = (float2*)(ws + 6144);   // 1024 x NPART float2
    unsigned char* Wbf = (unsigned char*)d_ws + 2 * 1024 * 1024;  // 41.4 MB

    const size_t wbf_bytes = (size_t)NK * 2 * NBLK * 64 * 256;
    const size_t need = 2ull * 1024 * 1024 + wbf_bytes;

    rowprep<<<BB, 64, 0, stream>>>(X, factor, xinv, fa, thr);
    if (ws_size >= need) {
        wconv<<<NK * NBLK, 256, 0, stream>>>(W, Wbf);
        gemm_mx<<<640, 256, 0, stream>>>(X, Wbf, label, xinv, partial, cosl);
    } else {
        gemm_stats<<<640, 256, 0, stream>>>(X, W, label, xinv, partial, cosl);
    }
    finalize_rows<<<BB / 4, 256, 0, stream>>>(partial, cosl, fa, thr, rowres);
    finalize_sum<<<1, BB, 0, stream>>>(rowres, out);
}

// Round 7
// 236.492 us; speedup vs baseline: 1.6787x; 1.6787x over previous
//
#include <hip/hip_runtime.h>
#include <hip/hip_bf16.h>
#include <math.h>

#define BB    1024
#define FIN   128
#define NOUT  10000
#define NBLK  79          // 128-col strips
#define NK    16
#define NPART (NBLK * 4)  // per (strip, wn, ch) partials
#define LDX   136         // LDS stride (shorts) for the X tile

typedef __attribute__((ext_vector_type(8))) short short8;
typedef __attribute__((ext_vector_type(4))) float floatx4;

__device__ __forceinline__ unsigned packbf(float a, float b) {
    __hip_bfloat162 h = __float22bfloat162_rn(make_float2(a, b));
    union { __hip_bfloat162 h2; unsigned u; } v;
    v.h2 = h;
    return v.u;
}

// async global->LDS, 16B per lane; LDS dest = wave-uniform base + lane*16.
__device__ __forceinline__ void async16(const void* g, void* l) {
    __builtin_amdgcn_global_load_lds(
        (const __attribute__((address_space(1))) unsigned int*)g,
        (__attribute__((address_space(3))) unsigned int*)l, 16, 0, 0);
}

// ---------------------------------------------------------------------------
// Kernel A: per-row input inverse-norm + margin params
__global__ void rowprep(const float* __restrict__ X, const float* __restrict__ factor,
                        float* __restrict__ xinv, float* __restrict__ fa_out,
                        float* __restrict__ thr_out) {
    int b = blockIdx.x;
    int lane = threadIdx.x;
    float v0 = X[b * FIN + lane];
    float v1 = X[b * FIN + 64 + lane];
    float s = v0 * v0 + v1 * v1;
    #pragma unroll
    for (int off = 32; off > 0; off >>= 1) s += __shfl_down(s, off);
    if (lane == 0) {
        float n = sqrtf(s);
        xinv[b] = 1.0f / fmaxf(n, 1e-12f);
        float fa = powf(1.5f, factor[b] * (1.0f / 12.0f)) * 0.5f;
        fa_out[b] = fa;
        thr_out[b] = (float)M_PI - fa;
    }
}

// ---------------------------------------------------------------------------
// Kernel W: one-time W conversion, LDS-staged & fully coalesced.
// Output layout (ch-major): [ch][k][strip][idx64][256B column]; for col o:
//   strip=o>>7, g=o&127, ch=(g>>5)&1, idx64=((g>>6)<<5)|(g&31).
// Within a column, true chunk tc (features tc*8..tc*8+7) sits at byte
// offset ((tc ^ (o&15)) * 16)  -> conflict-free b128 reads in gemm.
__global__ __launch_bounds__(256) void wconv(const float* __restrict__ W,
                                             unsigned char* __restrict__ Wbf) {
    __shared__ float xs2[128 * 128];   // [f][o] fp32 (64 KB)
    __shared__ float sq2[256];
    __shared__ float wis[128];

    const int tid = threadIdx.x;
    const int k = blockIdx.x / NBLK;
    const int strip = blockIdx.x - k * NBLK;
    const int o0 = strip * 128;

    // stage 128f x 128o = 4096 float4; 256 threads -> 16 iters
    #pragma unroll
    for (int it = 0; it < 16; it++) {
        int idx = it * 256 + tid;      // float4 index 0..4095
        int f = idx >> 5;
        int c4 = idx & 31;
        int o = o0 + c4 * 4;
        float4 v = make_float4(0.f, 0.f, 0.f, 0.f);
        if (o < NOUT)
            v = *(const float4*)(W + ((size_t)k * FIN + f) * NOUT + o);
        *(float4*)(xs2 + f * 128 + c4 * 4) = v;
    }
    __syncthreads();

    const int col = tid & 127;
    const int half = tid >> 7;
    float s = 0.0f;
    #pragma unroll 8
    for (int f2 = 0; f2 < 64; f2++) {
        float x = xs2[(half * 64 + f2) * 128 + col];
        s = fmaf(x, x, s);
    }
    sq2[half * 128 + col] = s;
    __syncthreads();
    if (tid < 128)
        wis[tid] = 1.0f / fmaxf(sqrtf(sq2[tid] + sq2[tid + 128]), 1e-12f);
    __syncthreads();

    const float wi = wis[col];
    const int ch = (col >> 5) & 1;
    const int idx64 = ((col >> 6) << 5) | (col & 31);
    unsigned char* colbase =
        Wbf + ((((size_t)ch * NK + k) * NBLK + strip) * 64 + idx64) * 256;
    #pragma unroll
    for (int tcl = 0; tcl < 8; tcl++) {
        int tc = half * 8 + tcl;
        float v0 = xs2[(tc * 8 + 0) * 128 + col] * wi;
        float v1 = xs2[(tc * 8 + 1) * 128 + col] * wi;
        float v2 = xs2[(tc * 8 + 2) * 128 + col] * wi;
        float v3 = xs2[(tc * 8 + 3) * 128 + col] * wi;
        float v4 = xs2[(tc * 8 + 4) * 128 + col] * wi;
        float v5 = xs2[(tc * 8 + 5) * 128 + col] * wi;
        float v6 = xs2[(tc * 8 + 6) * 128 + col] * wi;
        float v7 = xs2[(tc * 8 + 7) * 128 + col] * wi;
        uint4 u;
        u.x = packbf(v0, v1);
        u.y = packbf(v2, v3);
        u.z = packbf(v4, v5);
        u.w = packbf(v6, v7);
        *(uint4*)(colbase + ((tc ^ (col & 15)) * 16)) = u;
    }
}

// ---------------------------------------------------------------------------
// Kernel B: MFMA GEMM + max-over-k + partial online-softmax.
// ch-major ck order: for each column half, loop all 16 sub-centers then run
// a per-ch epilogue -> maxv live set is 32 VGPRs (was 64). (256,2) bound:
// empirically spill-free (r2-r4: 124 VGPR); (256,3) spilled (r6: 682 MB
// scratch writes).
__global__ __launch_bounds__(256, 2) void gemm_mx(
    const float* __restrict__ X, const unsigned char* __restrict__ Wbf,
    const int* __restrict__ label, const float* __restrict__ xinv,
    float2* __restrict__ partial, float* __restrict__ cosl) {

    __shared__ union {
        short xs[128 * LDX];   // 34816 B, X staging
        short bb[2][8192];     // 2 x 16 KB B buffers
    } u;

    const int tid  = threadIdx.x;
    const int lane = tid & 63;
    const int w    = tid >> 6;
    const int l15  = lane & 15;
    const int q    = lane >> 4;
    const int wm   = w & 1;
    const int wn   = w >> 1;

    // XCD-aware decode: ids {group*64 + y*8 + xcd} -> jb = group*8+xcd
    const int id    = blockIdx.x;
    const int group = id >> 6;
    const int sub   = id & 63;
    const int jb    = group * 8 + (sub & 7);
    const int y     = sub >> 3;
    if (jb >= NBLK) return;
    const int r0 = y * 128;
    const int o0 = jb * 128;

    // ---- stage X tile as bf16 with xinv folded ----
    #pragma unroll
    for (int it = 0; it < 16; it++) {
        int idx = it * 256 + tid;
        int row = idx >> 5;
        int c4  = idx & 31;
        const float4 v = *(const float4*)(X + (size_t)(r0 + row) * FIN + c4 * 4);
        float xi = xinv[r0 + row];
        uint2 p;
        p.x = packbf(v.x * xi, v.y * xi);
        p.y = packbf(v.z * xi, v.w * xi);
        *(uint2*)(u.xs + row * LDX + c4 * 4) = p;
    }
    __syncthreads();

    short8 af[4][4];
    #pragma unroll
    for (int mt = 0; mt < 4; mt++)
        #pragma unroll
        for (int kk = 0; kk < 4; kk++)
            af[mt][kk] = *(const short8*)(u.xs + (wm * 64 + mt * 16 + l15) * LDX + kk * 32 + q * 8);
    __syncthreads();   // X area now reusable as B buffers

    auto issue = [&](int ck) {
        const unsigned char* g = Wbf + ((size_t)ck * NBLK + jb) * 16384
                                 + (size_t)(w * 4) * 1024 + (size_t)lane * 16;
        short* d = u.bb[ck & 1] + w * 2048;
        #pragma unroll
        for (int i = 0; i < 4; i++) async16(g + i * 1024, d + i * 512);
    };

    issue(0);

    for (int ch = 0; ch < 2; ch++) {
        floatx4 maxv[4][2];
        #pragma unroll
        for (int mt = 0; mt < 4; mt++)
            #pragma unroll
            for (int n2 = 0; n2 < 2; n2++)
                #pragma unroll
                for (int r = 0; r < 4; r++)
                    maxv[mt][n2][r] = -INFINITY;

        for (int k = 0; k < NK; k++) {
            const int ck = ch * NK + k;
            __syncthreads();   // prefetch(ck) landed; prior buffer reads done
            if (ck < 2 * NK - 1) issue(ck + 1);
            const short* wt = u.bb[ck & 1];

            #pragma unroll
            for (int n2 = 0; n2 < 2; n2++) {
                const int bidx = wn * 32 + n2 * 16 + l15;   // column in buffer
                floatx4 acc[4];
                #pragma unroll
                for (int mt = 0; mt < 4; mt++) acc[mt] = (floatx4){0.f, 0.f, 0.f, 0.f};
                #pragma unroll
                for (int kk = 0; kk < 4; kk++) {
                    short8 bf = *(const short8*)(wt + bidx * 128 + (((kk * 4 + q) ^ l15) * 8));
                    #pragma unroll
                    for (int mt = 0; mt < 4; mt++)
                        acc[mt] = __builtin_amdgcn_mfma_f32_16x16x32_bf16(af[mt][kk], bf, acc[mt], 0, 0, 0);
                }
                #pragma unroll
                for (int mt = 0; mt < 4; mt++)
                    #pragma unroll
                    for (int r = 0; r < 4; r++)
                        maxv[mt][n2][r] = fmaxf(maxv[mt][n2][r], acc[mt][r]);
            }
        }

        // ---- per-ch epilogue: partial online-softmax over this wave's 2
        // column groups (label col excluded); register-only + global writes.
        #pragma unroll
        for (int mt = 0; mt < 4; mt++) {
            #pragma unroll
            for (int rr = 0; rr < 4; rr++) {
                int row = r0 + wm * 64 + mt * 16 + q * 4 + rr;
                int lb = label[row];
                float m = -1e30f, s = 0.f;
                #pragma unroll
                for (int n2 = 0; n2 < 2; n2++) {
                    int o = o0 + wn * 64 + ch * 32 + n2 * 16 + l15;
                    if (o < NOUT) {
                        float c = maxv[mt][n2][rr];
                        if (o == lb) {
                            cosl[row] = c;   // unique writer grid-wide
                        } else {
                            float l = 64.0f * fminf(fmaxf(c, -1.0f + 1e-6f), 1.0f - 1e-6f);
                            if (l > m) { s = s * __expf(m - l) + 1.0f; m = l; }
                            else       { s += __expf(l - m); }
                        }
                    }
                }
                #pragma unroll
                for (int off = 1; off <= 8; off <<= 1) {
                    float m2 = __shfl_xor(m, off);
                    float s2 = __shfl_xor(s, off);
                    float M = fmaxf(m, m2);
                    s = s * __expf(m - M) + s2 * __expf(m2 - M);
                    m = M;
                }
                if (l15 == 0)
                    partial[(size_t)row * NPART + jb * 4 + wn * 2 + ch] = make_float2(m, s);
            }
        }
    }
}

// ---------------------------------------------------------------------------
// Fallback GEMM (round-3 path) used when ws_size can't hold Wbf.
__global__ __launch_bounds__(256, 2) void gemm_stats(
    const float* __restrict__ X, const float* __restrict__ W,
    const int* __restrict__ label, const float* __restrict__ xinv,
    float2* __restrict__ partial, float* __restrict__ cosl) {

    __shared__ short xs[128 * LDX];
    __shared__ short wt[128 * LDX];
    __shared__ float sqs[128][2];

    const int tid  = threadIdx.x;
    const int lane = tid & 63;
    const int w    = tid >> 6;
    const int l15  = lane & 15;
    const int q    = lane >> 4;
    const int wm   = w & 1;
    const int wn   = w >> 1;

    const int id    = blockIdx.x;
    const int group = id >> 6;
    const int sub   = id & 63;
    const int jb    = group * 8 + (sub & 7);
    const int y     = sub >> 3;
    if (jb >= NBLK) return;
    const int r0 = y * 128;
    const int o0 = jb * 128;

    #pragma unroll
    for (int it = 0; it < 16; it++) {
        int idx = it * 256 + tid;
        int row = idx >> 5;
        int c4  = idx & 31;
        const float4 v = *(const float4*)(X + (size_t)(r0 + row) * FIN + c4 * 4);
        uint2 p;
        p.x = packbf(v.x, v.y);
        p.y = packbf(v.z, v.w);
        *(uint2*)(xs + row * LDX + c4 * 4) = p;
    }

    const int st_o = (w & 1) * 64 + lane;
    const int st_f = (w >> 1) * 64;
    const int st_h = w >> 1;
    const int go   = o0 + st_o;
    const bool ov  = go < NOUT;

    float rw[64];
    {
        const float* Wp = W + (size_t)st_f * NOUT + go;
        #pragma unroll
        for (int g = 0; g < 16; g++)
            #pragma unroll
            for (int c = 0; c < 4; c++)
                rw[g * 4 + c] = ov ? Wp[(size_t)(g * 4 + c) * NOUT] : 0.0f;
    }
    __syncthreads();

    short8 af[4][4];
    #pragma unroll
    for (int mt = 0; mt < 4; mt++)
        #pragma unroll
        for (int kk = 0; kk < 4; kk++)
            af[mt][kk] = *(const short8*)(xs + (wm * 64 + mt * 16 + l15) * LDX + kk * 32 + q * 8);

    floatx4 maxv[4][4];
    #pragma unroll
    for (int mt = 0; mt < 4; mt++)
        #pragma unroll
        for (int nt = 0; nt < 4; nt++)
            #pragma unroll
            for (int r = 0; r < 4; r++)
                maxv[mt][nt][r] = -INFINITY;

    for (int k = 0; k < NK; k++) {
        float sq = 0.0f;
        uint2 pk[16];
        #pragma unroll
        for (int g = 0; g < 16; g++) {
            float a0 = rw[g * 4 + 0], a1 = rw[g * 4 + 1];
            float a2 = rw[g * 4 + 2], a3 = rw[g * 4 + 3];
            sq = fmaf(a0, a0, sq); sq = fmaf(a1, a1, sq);
            sq = fmaf(a2, a2, sq); sq = fmaf(a3, a3, sq);
            pk[g].x = packbf(a0, a1);
            pk[g].y = packbf(a2, a3);
        }
        __syncthreads();
        #pragma unroll
        for (int g = 0; g < 16; g++)
            *(uint2*)(wt + st_o * LDX + st_f + g * 4) = pk[g];
        sqs[st_o][st_h] = sq;
        __syncthreads();

        if (k < NK - 1) {
            const float* Wn = W + ((size_t)(k + 1) * FIN + st_f) * NOUT + go;
            #pragma unroll
            for (int g = 0; g < 16; g++)
                #pragma unroll
                for (int c = 0; c < 4; c++)
                    rw[g * 4 + c] = ov ? Wn[(size_t)(g * 4 + c) * NOUT] : 0.0f;
        }

        float wv[4];
        #pragma unroll
        for (int nt = 0; nt < 4; nt++) {
            int col = wn * 64 + nt * 16 + l15;
            wv[nt] = 1.0f / fmaxf(sqrtf(sqs[col][0] + sqs[col][1]), 1e-12f);
        }

        #pragma unroll
        for (int h = 0; h < 2; h++) {
            floatx4 acc[4][2];
            #pragma unroll
            for (int mt = 0; mt < 4; mt++) {
                acc[mt][0] = (floatx4){0.f, 0.f, 0.f, 0.f};
                acc[mt][1] = (floatx4){0.f, 0.f, 0.f, 0.f};
            }
            #pragma unroll
            for (int kk = 0; kk < 4; kk++) {
                short8 bf0 = *(const short8*)(wt + (wn * 64 + (h * 2 + 0) * 16 + l15) * LDX + kk * 32 + q * 8);
                short8 bf1 = *(const short8*)(wt + (wn * 64 + (h * 2 + 1) * 16 + l15) * LDX + kk * 32 + q * 8);
                #pragma unroll
                for (int mt = 0; mt < 4; mt++) {
                    acc[mt][0] = __builtin_amdgcn_mfma_f32_16x16x32_bf16(af[mt][kk], bf0, acc[mt][0], 0, 0, 0);
                    acc[mt][1] = __builtin_amdgcn_mfma_f32_16x16x32_bf16(af[mt][kk], bf1, acc[mt][1], 0, 0, 0);
                }
            }
            #pragma unroll
            for (int mt = 0; mt < 4; mt++)
                #pragma unroll
                for (int n2 = 0; n2 < 2; n2++)
                    #pragma unroll
                    for (int r = 0; r < 4; r++)
                        maxv[mt][h * 2 + n2][r] =
                            fmaxf(maxv[mt][h * 2 + n2][r], acc[mt][n2][r] * wv[h * 2 + n2]);
        }
    }

    #pragma unroll
    for (int mt = 0; mt < 4; mt++) {
        #pragma unroll
        for (int rr = 0; rr < 4; rr++) {
            int row = r0 + wm * 64 + mt * 16 + q * 4 + rr;
            float xi = xinv[row];
            int lb = label[row];
            float m = -1e30f, s = 0.f;
            #pragma unroll
            for (int nt = 0; nt < 4; nt++) {
                int o = o0 + wn * 64 + nt * 16 + l15;
                if (o < NOUT) {
                    float c = maxv[mt][nt][rr] * xi;
                    if (o == lb) {
                        cosl[row] = c;
                    } else {
                        float l = 64.0f * fminf(fmaxf(c, -1.0f + 1e-6f), 1.0f - 1e-6f);
                        if (l > m) { s = s * __expf(m - l) + 1.0f; m = l; }
                        else       { s += __expf(l - m); }
                    }
                }
            }
            #pragma unroll
            for (int off = 1; off <= 8; off <<= 1) {
                float m2 = __shfl_xor(m, off);
                float s2 = __shfl_xor(s, off);
                float M = fmaxf(m, m2);
                s = s * __expf(m - M) + s2 * __expf(m2 - M);
                m = M;
            }
            if (l15 == 0) {
                partial[(size_t)row * NPART + jb * 4 + wn * 2 + 0] = make_float2(m, s);
                partial[(size_t)row * NPART + jb * 4 + wn * 2 + 1] = make_float2(-1e30f, 0.f);
            }
        }
    }
}

// ---------------------------------------------------------------------------
// Kernel C1: per-row combine + margin -> (loss, corr) per row. No atomics.
__global__ void finalize_rows(const float2* __restrict__ partial, const float* __restrict__ cosl,
                              const float* __restrict__ fa, const float* __restrict__ thr,
                              float2* __restrict__ rowres) {
    int w = threadIdx.x >> 6;
    int lane = threadIdx.x & 63;
    int b = blockIdx.x * 4 + w;
    float m = -1e30f, s = 0.0f;
    for (int j = lane; j < NPART; j += 64) {
        float2 p = partial[(size_t)b * NPART + j];
        float M = fmaxf(m, p.x);
        s = s * __expf(m - M) + p.y * __expf(p.x - M);
        m = M;
    }
    #pragma unroll
    for (int off = 1; off < 64; off <<= 1) {
        float m2 = __shfl_xor(m, off);
        float s2 = __shfl_xor(s, off);
        float M = fmaxf(m, m2);
        s = s * __expf(m - M) + s2 * __expf(m2 - M);
        m = M;
    }
    if (lane == 0) {
        float c = fminf(fmaxf(cosl[b], -1.0f + 1e-6f), 1.0f - 1e-6f);
        float theta = acosf(c);
        float ll = (theta > thr[b]) ? 64.0f * c : 64.0f * cosf(theta + fa[b]);
        float M = fmaxf(m, ll);
        float S = s * __expf(m - M) + __expf(ll - M);
        rowres[b] = make_float2(M + logf(S) - ll, (ll > m) ? 100.0f : 0.0f);
    }
}

// Kernel C2: deterministic tree reduce of 1024 rows -> 2 scalars.
__global__ void finalize_sum(const float2* __restrict__ rowres, float* __restrict__ out) {
    __shared__ float sl[1024];
    __shared__ float sc[1024];
    int b = threadIdx.x;
    float2 v = rowres[b];
    sl[b] = v.x;
    sc[b] = v.y;
    __syncthreads();
    for (int st = 512; st > 0; st >>= 1) {
        if (b < st) { sl[b] += sl[b + st]; sc[b] += sc[b + st]; }
        __syncthreads();
    }
    if (b == 0) {
        out[0] = sl[0] * (1.0f / 1024.0f);
        out[1] = sc[0] * (1.0f / 1024.0f);
    }
}

// ---------------------------------------------------------------------------
extern "C" void kernel_launch(void* const* d_in, const int* in_sizes, int n_in,
                              void* d_out, int out_size, void* d_ws, size_t ws_size,
                              hipStream_t stream) {
    const float* X      = (const float*)d_in[0];
    const float* factor = (const float*)d_in[1];
    const int*   label  = (const int*)d_in[2];
    const float* W      = (const float*)d_in[3];
    float* out = (float*)d_out;
    float* ws  = (float*)d_ws;

    float*  xinv = ws;                        // 1024
    float*  fa   = ws + 1024;                 // 1024
    float*  thr  = ws + 2048;                 // 1024
    float*  cosl = ws + 3072;                 // 1024
    float2* rowres = (float2*)(ws + 4096);    // 1024 float2
    float2* partial = (float2*)(ws + 6144);   // 1024 x NPART float2 (~2.6 MB)
    unsigned char* Wbf = (unsigned char*)d_ws + 4 * 1024 * 1024;  // 41.4 MB

    const size_t wbf_bytes = (size_t)NK * 2 * NBLK * 64 * 256;
    const size_t need = 4ull * 1024 * 1024 + wbf_bytes;

    rowprep<<<BB, 64, 0, stream>>>(X, factor, xinv, fa, thr);
    if (ws_size >= need) {
        wconv<<<NK * NBLK, 256, 0, stream>>>(W, Wbf);
        gemm_mx<<<640, 256, 0, stream>>>(X, Wbf, label, xinv, partial, cosl);
    } else {
        gemm_stats<<<640, 256, 0, stream>>>(X, W, label, xinv, partial, cosl);
    }
    finalize_rows<<<BB / 4, 256, 0, stream>>>(partial, cosl, fa, thr, rowres);
    finalize_sum<<<1, BB, 0, stream>>>(rowres, out);
}